// Round 1
// baseline (2543.718 us; speedup 1.0000x reference)
//
#include <hip/hip_runtime.h>
#include <math.h>

// Problem constants
#define B 2
#define CH 128       // cin = cout = 128
#define H 96
#define W 128
#define HP 104       // H + 2*K
#define WP 136       // W + 2*K
#define KPAD 4
#define NSHIFT 81
#define NBR 6
#define HW (H*W)         // 12288
#define HWP (HP*WP)      // 14144

__device__ __constant__ int d_radius[NBR] = {1, 3, 5, 9, 13, 21};

// ---------------------------------------------------------------------------
// xn[b][g][h][w] = sqrt(sum_c x[b][g*32+c][h][w]^2)
__global__ __launch_bounds__(256) void xn_kernel(const float* __restrict__ x,
                                                 float* __restrict__ xn) {
    int idx = blockIdx.x * 256 + threadIdx.x;
    if (idx >= B * 4 * HW) return;
    int pix = idx % HW;
    int bg  = idx / HW;
    int g = bg & 3, b = bg >> 2;
    const float* xp = x + (size_t)(b * CH + g * 32) * HW + pix;
    float s = 0.f;
    #pragma unroll
    for (int c = 0; c < 32; c++) { float v = xp[(size_t)c * HW]; s += v * v; }
    xn[idx] = sqrtf(s);
}

// yn[b][g][ph][pw] = sqrt(sum_c yg[b][g*32+c][ph][pw]^2)
__global__ __launch_bounds__(256) void yn_kernel(const float* __restrict__ yg,
                                                 float* __restrict__ yn) {
    int idx = blockIdx.x * 256 + threadIdx.x;
    if (idx >= B * 4 * HWP) return;
    int pix = idx % HWP;
    int bg  = idx / HWP;
    int g = bg & 3, b = bg >> 2;
    const float* yp = yg + (size_t)(b * CH + g * 32) * HWP + pix;
    float s = 0.f;
    #pragma unroll
    for (int c = 0; c < 32; c++) { float v = yp[(size_t)c * HWP]; s += v * v; }
    yn[idx] = sqrtf(s);
}

// ---------------------------------------------------------------------------
// Dilated 3x3 conv over reflect-padded y, zero padding d on the padded grid.
// Output yg[b][co][ph][pw], ph in [0,104), pw in [0,136).
// Block tile: 64 co x (4 rows x 16 cols). 256 threads, micro-tile 4co x 4px.
// Grid: (colTiles=9, rowTiles=26, b*2 + coTile)
#define CI_PER 2
__global__ __launch_bounds__(256) void conv_kernel(const float* __restrict__ y,
                                                   const float* __restrict__ wts,
                                                   const float* __restrict__ biases,
                                                   float* __restrict__ yg,
                                                   int br, int d) {
    const int tid = threadIdx.x;
    const int ty = tid >> 4;          // 0..15 (co direction)
    const int tx = tid & 15;          // 0..15 (pixel direction)
    const int row_local = tx >> 2;    // 0..3
    const int col_local = (tx & 3) * 4;

    const int C  = blockIdx.x * 16;          // col base (pw)
    const int R  = blockIdx.y * 4;           // row base (ph)
    const int b  = blockIdx.z >> 1;
    const int co0 = (blockIdx.z & 1) * 64;

    __shared__ float w_lds[CI_PER][9][64];       // [cc][tap][co]
    __shared__ float in_lds[CI_PER * 12 * 67];   // [cc*12 + kh*4 + r][lc], stride 67

    float acc[4][4];
    #pragma unroll
    for (int i = 0; i < 4; i++)
        #pragma unroll
        for (int j = 0; j < 4; j++) acc[i][j] = 0.f;

    const float* yb = y + (size_t)b * CH * HW;
    const float* wp = wts + (size_t)br * CH * (CH * 9);
    const int w_span = 16 + 2 * d;

    for (int ci0 = 0; ci0 < CH; ci0 += CI_PER) {
        // ---- stage weights: w_lds[cc][tap][co], co in [co0, co0+64)
        for (int idx = tid; idx < CI_PER * 576; idx += 256) {
            int cc  = idx / 576;
            int rem = idx - cc * 576;
            int co  = rem / 9;
            int tap = rem - co * 9;
            w_lds[cc][tap][co] =
                wp[(size_t)(co0 + co) * (CH * 9) + (size_t)(ci0 + cc) * 9 + tap];
        }
        // ---- stage input rows: for each (cc, kh, r): row R+r+(kh-1)*d,
        //      cols [C-d, C+15+d], zero outside padded grid, reflect inside.
        for (int idx = tid; idx < CI_PER * 12 * 64; idx += 256) {
            int lc  = idx & 63;
            int rid = idx >> 6;                 // 0..23
            if (lc < w_span) {
                int cc  = rid / 12;
                int rem = rid - cc * 12;
                int kh  = rem >> 2;
                int r   = rem & 3;
                int gr = R + r + (kh - 1) * d;  // row in padded (104) grid
                int gc = C - d + lc;            // col in padded (136) grid
                float v = 0.f;
                if ((unsigned)gr < (unsigned)HP && (unsigned)gc < (unsigned)WP) {
                    int yr = gr - KPAD;
                    yr = yr < 0 ? -yr : (yr >= H ? 2 * (H - 1) - yr : yr);
                    int yc = gc - KPAD;
                    yc = yc < 0 ? -yc : (yc >= W ? 2 * (W - 1) - yc : yc);
                    v = yb[(size_t)(ci0 + cc) * HW + yr * W + yc];
                }
                in_lds[rid * 67 + lc] = v;
            }
        }
        __syncthreads();

        #pragma unroll
        for (int cc = 0; cc < CI_PER; cc++) {
            #pragma unroll
            for (int kh = 0; kh < 3; kh++) {
                #pragma unroll
                for (int kw = 0; kw < 3; kw++) {
                    float wv[4], iv[4];
                    #pragma unroll
                    for (int i = 0; i < 4; i++) wv[i] = w_lds[cc][kh * 3 + kw][ty * 4 + i];
                    int base = (cc * 12 + kh * 4 + row_local) * 67 + col_local + kw * d;
                    #pragma unroll
                    for (int j = 0; j < 4; j++) iv[j] = in_lds[base + j];
                    #pragma unroll
                    for (int i = 0; i < 4; i++)
                        #pragma unroll
                        for (int j = 0; j < 4; j++) acc[i][j] += wv[i] * iv[j];
                }
            }
        }
        __syncthreads();
    }

    // ---- epilogue: bias + store
    const int ph = R + row_local;
    #pragma unroll
    for (int i = 0; i < 4; i++) {
        int co = co0 + ty * 4 + i;
        float bv = biases[br * CH + co];
        float* og = yg + (size_t)(b * CH + co) * HWP + ph * WP + C + col_local;
        #pragma unroll
        for (int j = 0; j < 4; j++) {
            int pw = C + col_local + j;
            if (pw < WP) og[j] = acc[i][j] + bv;
        }
    }
}

// ---------------------------------------------------------------------------
// Correlation: for one branch br and one (b,g), block covers 4 rows x 64 cols
// of output. acc[81] in registers; per channel-pair stage 12x72 y-tile in LDS.
// Grid: (2, 24, b*4+g)
#define CH_PER 2
__global__ __launch_bounds__(256) void corr_kernel(const float* __restrict__ x,
                                                   const float* __restrict__ yg,
                                                   const float* __restrict__ xn,
                                                   const float* __restrict__ yn,
                                                   float* __restrict__ out,
                                                   int br) {
    const int tid = threadIdx.x;
    const int row = tid >> 6;     // 0..3
    const int col = tid & 63;     // 0..63
    const int W0 = blockIdx.x * 64;
    const int H0 = blockIdx.y * 4;
    const int g = blockIdx.z & 3, b = blockIdx.z >> 2;
    const int hh = H0 + row, ww = W0 + col;

    __shared__ float yt[CH_PER][12 * 72];

    float acc[NSHIFT];
    #pragma unroll
    for (int s = 0; s < NSHIFT; s++) acc[s] = 0.f;

    const float* ygb = yg + (size_t)(b * CH + g * 32) * HWP;
    const float* xb  = x + (size_t)(b * CH + g * 32) * HW + hh * W + ww;

    for (int c0 = 0; c0 < 32; c0 += CH_PER) {
        for (int idx = tid; idx < CH_PER * 12 * 72; idx += 256) {
            int cc  = idx / (12 * 72);
            int rem = idx - cc * (12 * 72);
            int r   = rem / 72;
            int lc  = rem - r * 72;
            yt[cc][r * 72 + lc] =
                ygb[(size_t)(c0 + cc) * HWP + (H0 + r) * WP + W0 + lc];
        }
        __syncthreads();
        #pragma unroll
        for (int cc = 0; cc < CH_PER; cc++) {
            float xv = xb[(size_t)(c0 + cc) * HW];
            #pragma unroll
            for (int sx = 0; sx < 9; sx++) {
                int base = (row + sx) * 72 + col;
                #pragma unroll
                for (int sy = 0; sy < 9; sy++)
                    acc[sx * 9 + sy] += xv * yt[cc][base + sy];
            }
        }
        __syncthreads();
    }

    float xnv = xn[(size_t)(b * 4 + g) * HW + hh * W + ww];
    const float* ynb = yn + (size_t)(b * 4 + g) * HWP;
    float* ob = out + ((size_t)(b * 24 + br * 4 + g) * NSHIFT) * HW + hh * W + ww;
    #pragma unroll
    for (int sx = 0; sx < 9; sx++) {
        #pragma unroll
        for (int sy = 0; sy < 9; sy++) {
            float ynv = ynb[(H0 + row + sx) * WP + W0 + col + sy];
            float den = xnv * ynv;
            den = den > 1e-8f ? den : 1e-8f;
            ob[(size_t)(sx * 9 + sy) * HW] = acc[sx * 9 + sy] / den;
        }
    }
}

// ---------------------------------------------------------------------------
extern "C" void kernel_launch(void* const* d_in, const int* in_sizes, int n_in,
                              void* d_out, int out_size, void* d_ws, size_t ws_size,
                              hipStream_t stream) {
    const float* x       = (const float*)d_in[0];
    const float* y       = (const float*)d_in[1];
    const float* weights = (const float*)d_in[2];
    const float* biases  = (const float*)d_in[3];
    float* out = (float*)d_out;

    // workspace layout (floats): yg | yn | xn
    float* yg = (float*)d_ws;                       // B*CH*HP*WP = 3,620,864
    float* yn = yg + (size_t)B * CH * HWP;          // B*4*HP*WP  =   113,152
    float* xn = yn + (size_t)B * 4 * HWP;           // B*4*H*W    =    98,304

    static const int radii[NBR] = {1, 3, 5, 9, 13, 21};

    xn_kernel<<<(B * 4 * HW + 255) / 256, 256, 0, stream>>>(x, xn);

    for (int br = 0; br < NBR; br++) {
        int d = radii[br];
        conv_kernel<<<dim3(9, 26, 4), 256, 0, stream>>>(y, weights, biases, yg, br, d);
        yn_kernel<<<(B * 4 * HWP + 255) / 256, 256, 0, stream>>>(yg, yn);
        corr_kernel<<<dim3(2, 24, B * 4), 256, 0, stream>>>(x, yg, xn, yn, out, br);
    }
}

// Round 2
// 652.599 us; speedup vs baseline: 3.8978x; 3.8978x over previous
//
#include <hip/hip_runtime.h>
#include <math.h>

#define B 2
#define CH 128
#define H 96
#define W 128
#define HP 104
#define WP 136
#define KPAD 4
#define NSHIFT 81
#define NBR 6
#define HW (H*W)         // 12288
#define HWP (HP*WP)      // 14144
#define NTILE 111        // ceil(14144/128)

typedef _Float16 half8 __attribute__((ext_vector_type(8)));
typedef float floatx4 __attribute__((ext_vector_type(4)));

__device__ __constant__ int d_radius[NBR] = {1, 3, 5, 9, 13, 21};

__device__ __forceinline__ void async16(const _Float16* g, _Float16* l) {
    __builtin_amdgcn_global_load_lds(
        (const __attribute__((address_space(1))) unsigned int*)g,
        (__attribute__((address_space(3))) unsigned int*)l, 16, 0, 0);
}

// ---------------------------------------------------------------------------
// y[b][c][hw] (f32) -> yt16[b][hw][c] (f16) channels-last
__global__ __launch_bounds__(256) void convert_y_kernel(const float* __restrict__ y,
                                                        _Float16* __restrict__ yt16) {
    int gid = blockIdx.x * 256 + threadIdx.x;
    if (gid >= B * HW * CH) return;
    int c = gid & 127;
    int rest = gid >> 7;
    int hw = rest % HW;
    int b = rest / HW;
    yt16[gid] = (_Float16)y[((size_t)(b * CH + c)) * HW + hw];
}

// weights[br][co][ci][tap] (f32) -> w16t[br][tap][co][ci] (f16); also zero zbuf
__global__ __launch_bounds__(256) void convert_w_kernel(const float* __restrict__ w,
                                                        _Float16* __restrict__ w16t,
                                                        _Float16* __restrict__ zbuf) {
    int gid = blockIdx.x * 256 + threadIdx.x;
    if (gid < 256) zbuf[gid] = (_Float16)0.0f;
    if (gid >= NBR * 9 * CH * CH) return;
    int ci = gid & 127;
    int co = (gid >> 7) & 127;
    int rest = gid >> 14;       // br*9 + tap
    int tap = rest % 9;
    int br = rest / 9;
    w16t[gid] = (_Float16)w[(((size_t)(br * CH + co)) * CH + ci) * 9 + tap];
}

// ---------------------------------------------------------------------------
__global__ __launch_bounds__(256) void xn_kernel(const float* __restrict__ x,
                                                 float* __restrict__ xn) {
    int idx = blockIdx.x * 256 + threadIdx.x;
    if (idx >= B * 4 * HW) return;
    int pix = idx % HW;
    int bg  = idx / HW;
    int g = bg & 3, b = bg >> 2;
    const float* xp = x + (size_t)(b * CH + g * 32) * HW + pix;
    float s = 0.f;
    #pragma unroll
    for (int c = 0; c < 32; c++) { float v = xp[(size_t)c * HW]; s += v * v; }
    xn[idx] = sqrtf(s);
}

// yn over G branches: yn_all[brl][b][g][pix]
__global__ __launch_bounds__(256) void yn_kernel(const float* __restrict__ yg_all,
                                                 float* __restrict__ yn_all, int total) {
    int idx = blockIdx.x * 256 + threadIdx.x;
    if (idx >= total) return;
    int pix = idx % HWP;
    int rest = idx / HWP;        // brl*8 + b*4 + g
    int bg = rest & 7;
    int brl = rest >> 3;
    int g = bg & 3, b = bg >> 2;
    const float* yp = yg_all + ((size_t)((brl * B + b) * CH) + g * 32) * HWP + pix;
    float s = 0.f;
    #pragma unroll
    for (int c = 0; c < 32; c++) { float v = yp[(size_t)c * HWP]; s += v * v; }
    yn_all[idx] = sqrtf(s);
}

// ---------------------------------------------------------------------------
// Implicit-GEMM dilated conv, f16 MFMA. Per block: 128 co x 128 pixels.
// Grid: (NTILE, G, B); blockIdx.y = branch-local.
__global__ __launch_bounds__(256) void conv_mfma(const _Float16* __restrict__ yt16,
                                                 const _Float16* __restrict__ w16t,
                                                 const _Float16* __restrict__ zbuf,
                                                 const float* __restrict__ biases,
                                                 float* __restrict__ yg_all,
                                                 int br0) {
    const int tid = threadIdx.x;
    const int lane = tid & 63;
    const int wv = tid >> 6;
    const int tile = blockIdx.x;
    const int brl = blockIdx.y;
    const int b = blockIdx.z;
    const int br = br0 + brl;
    const int d = d_radius[br];
    const int px0 = tile * 128;

    __shared__ __align__(16) _Float16 Al[128 * 32];
    __shared__ __align__(16) _Float16 Bl[128 * 32];

    const int l16 = tid & 3;
    int ph[2], pw[2];
    bool pval[2];
    #pragma unroll
    for (int s = 0; s < 2; ++s) {
        int pixl = s * 64 + (tid >> 2);
        int pix = px0 + pixl;
        pval[s] = pix < HWP;
        int phh = pix / WP;
        ph[s] = phh; pw[s] = pix - phh * WP;
    }

    const _Float16* ytb = yt16 + (size_t)b * HW * CH;
    const _Float16* wbr = w16t + (size_t)br * 9 * CH * CH;

    floatx4 acc[4][4];
    #pragma unroll
    for (int i = 0; i < 4; i++)
        #pragma unroll
        for (int j = 0; j < 4; j++) {
            floatx4 z = {0.f, 0.f, 0.f, 0.f};
            acc[i][j] = z;
        }

    const int mrow = (wv & 1) * 64 + (lane & 15);
    const int ncol = (wv >> 1) * 64 + (lane & 15);
    const int kq = (lane >> 4) * 8;

    for (int tap = 0; tap < 9; ++tap) {
        const int dkh = (tap / 3 - 1) * d;
        const int dkw = (tap % 3 - 1) * d;
        const _Float16* brow[2];
        #pragma unroll
        for (int s = 0; s < 2; ++s) {
            int gr = ph[s] + dkh, gc = pw[s] + dkw;
            bool v = pval[s] && ((unsigned)gr < (unsigned)HP) && ((unsigned)gc < (unsigned)WP);
            const _Float16* p;
            if (v) {
                int yr = gr - KPAD; yr = yr < 0 ? -yr : (yr >= H ? 2 * (H - 1) - yr : yr);
                int yc = gc - KPAD; yc = yc < 0 ? -yc : (yc >= W ? 2 * (W - 1) - yc : yc);
                p = ytb + ((size_t)(yr * W + yc)) * CH + l16 * 8;
            } else {
                p = zbuf + l16 * 8;
            }
            brow[s] = p;
        }
        const _Float16* wa = wbr + tap * CH * CH + (tid >> 2) * CH + l16 * 8;

        for (int ck = 0; ck < 4; ++ck) {
            const int ci0 = ck * 32;
            // stage A (weights): rows = co, 32 ci each
            async16(wa + ci0,            Al + wv * 512);
            async16(wa + 64 * CH + ci0,  Al + 2048 + wv * 512);
            // stage B (gathered input rows): rows = pixels, 32 ci each
            async16(brow[0] + ci0,       Bl + wv * 512);
            async16(brow[1] + ci0,       Bl + 2048 + wv * 512);
            __syncthreads();

            half8 af[4], bf[4];
            #pragma unroll
            for (int i = 0; i < 4; i++) af[i] = *(const half8*)&Al[(mrow + i * 16) * 32 + kq];
            #pragma unroll
            for (int j = 0; j < 4; j++) bf[j] = *(const half8*)&Bl[(ncol + j * 16) * 32 + kq];
            #pragma unroll
            for (int i = 0; i < 4; i++)
                #pragma unroll
                for (int j = 0; j < 4; j++)
                    acc[i][j] = __builtin_amdgcn_mfma_f32_16x16x32_f16(af[i], bf[j], acc[i][j], 0, 0, 0);
            __syncthreads();
        }
    }

    // epilogue: bias + store (C layout: n = lane&15, m = (lane>>4)*4 + reg)
    float* ygb = yg_all + ((size_t)(brl * B + b)) * CH * HWP;
    #pragma unroll
    for (int i = 0; i < 4; i++) {
        int m0 = (wv & 1) * 64 + i * 16 + (lane >> 4) * 4;
        #pragma unroll
        for (int j = 0; j < 4; j++) {
            int pix = px0 + (wv >> 1) * 64 + j * 16 + (lane & 15);
            if (pix < HWP) {
                #pragma unroll
                for (int r = 0; r < 4; r++) {
                    int co = m0 + r;
                    ygb[(size_t)co * HWP + pix] = acc[i][j][r] + biases[br * CH + co];
                }
            }
        }
    }
}

// ---------------------------------------------------------------------------
// Correlation: block = 4 rows x 64 cols of one (brl,b,g). Grid: (2, 24, 8*G)
#define CH_PER 4
__global__ __launch_bounds__(256) void corr_kernel(const float* __restrict__ x,
                                                   const float* __restrict__ yg_all,
                                                   const float* __restrict__ xn,
                                                   const float* __restrict__ yn_all,
                                                   float* __restrict__ out,
                                                   int br0) {
    const int tid = threadIdx.x;
    const int row = tid >> 6;
    const int col = tid & 63;
    const int W0 = blockIdx.x * 64;
    const int H0 = blockIdx.y * 4;
    int z = blockIdx.z;
    int bg = z & 7;
    int brl = z >> 3;
    int br = br0 + brl;
    int g = bg & 3, b = bg >> 2;
    const int hh = H0 + row, ww = W0 + col;

    __shared__ float yt[CH_PER][12 * 72];

    float acc[NSHIFT];
    #pragma unroll
    for (int s = 0; s < NSHIFT; s++) acc[s] = 0.f;

    const float* ygb = yg_all + ((size_t)((brl * B + b) * CH) + g * 32) * HWP;
    const float* xb  = x + (size_t)(b * CH + g * 32) * HW + hh * W + ww;

    for (int c0 = 0; c0 < 32; c0 += CH_PER) {
        for (int idx = tid; idx < CH_PER * 12 * 72; idx += 256) {
            int cc  = idx / (12 * 72);
            int rem = idx - cc * (12 * 72);
            int r   = rem / 72;
            int lc  = rem - r * 72;
            yt[cc][r * 72 + lc] =
                ygb[(size_t)(c0 + cc) * HWP + (H0 + r) * WP + W0 + lc];
        }
        __syncthreads();
        #pragma unroll
        for (int cc = 0; cc < CH_PER; cc++) {
            float xv = xb[(size_t)(c0 + cc) * HW];
            #pragma unroll
            for (int sx = 0; sx < 9; sx++) {
                int base = (row + sx) * 72 + col;
                #pragma unroll
                for (int sy = 0; sy < 9; sy++)
                    acc[sx * 9 + sy] += xv * yt[cc][base + sy];
            }
        }
        __syncthreads();
    }

    float xnv = xn[(size_t)(b * 4 + g) * HW + hh * W + ww];
    const float* ynb = yn_all + ((size_t)((brl * B + b) * 4 + g)) * HWP;
    float* ob = out + ((size_t)(b * 24 + br * 4 + g) * NSHIFT) * HW + hh * W + ww;
    #pragma unroll
    for (int sx = 0; sx < 9; sx++) {
        #pragma unroll
        for (int sy = 0; sy < 9; sy++) {
            float ynv = ynb[(H0 + row + sx) * WP + W0 + col + sy];
            float den = xnv * ynv;
            den = den > 1e-8f ? den : 1e-8f;
            ob[(size_t)(sx * 9 + sy) * HW] = acc[sx * 9 + sy] / den;
        }
    }
}

// ---------------------------------------------------------------------------
extern "C" void kernel_launch(void* const* d_in, const int* in_sizes, int n_in,
                              void* d_out, int out_size, void* d_ws, size_t ws_size,
                              hipStream_t stream) {
    const float* x       = (const float*)d_in[0];
    const float* y       = (const float*)d_in[1];
    const float* weights = (const float*)d_in[2];
    const float* biases  = (const float*)d_in[3];
    float* out = (float*)d_out;

    const size_t yg_b = (size_t)B * CH * HWP * 4;   // 14,483,456
    const size_t yn_b = (size_t)B * 4 * HWP * 4;    //    452,608
    const size_t xn_b = (size_t)B * 4 * HW * 4;     //    393,216
    const size_t yt_b = (size_t)B * HW * CH * 2;    //  6,291,456
    const size_t wt_b = (size_t)NBR * 9 * CH * CH * 2; // 1,769,472
    const size_t zb_b = 1024;

    int G = 6;
    {
        auto need = [&](int g) {
            return (size_t)g * (yg_b + yn_b) + xn_b + yt_b + wt_b + zb_b + 4096;
        };
        if (need(6) > ws_size) G = 3;
        if ((size_t)G * (yg_b + yn_b) + xn_b + yt_b + wt_b + zb_b + 4096 > ws_size) G = 2;
        if ((size_t)G * (yg_b + yn_b) + xn_b + yt_b + wt_b + zb_b + 4096 > ws_size) G = 1;
    }

    char* p = (char*)d_ws;
    float* yg_all = (float*)p; p += (size_t)G * yg_b;
    float* yn_all = (float*)p; p += (size_t)G * yn_b;
    float* xn     = (float*)p; p += xn_b;
    _Float16* yt16 = (_Float16*)p; p += yt_b;
    _Float16* w16t = (_Float16*)p; p += wt_b;
    _Float16* zbuf = (_Float16*)p;

    convert_y_kernel<<<(B * HW * CH + 255) / 256, 256, 0, stream>>>(y, yt16);
    convert_w_kernel<<<(NBR * 9 * CH * CH + 255) / 256, 256, 0, stream>>>(weights, w16t, zbuf);
    xn_kernel<<<(B * 4 * HW + 255) / 256, 256, 0, stream>>>(x, xn);

    for (int br0 = 0; br0 < NBR; br0 += G) {
        conv_mfma<<<dim3(NTILE, G, B), 256, 0, stream>>>(yt16, w16t, zbuf, biases, yg_all, br0);
        int tot = G * B * 4 * HWP;
        yn_kernel<<<(tot + 255) / 256, 256, 0, stream>>>(yg_all, yn_all, tot);
        corr_kernel<<<dim3(2, 24, 8 * G), 256, 0, stream>>>(x, yg_all, xn, yn_all, out, br0);
    }
}

// Round 3
// 382.572 us; speedup vs baseline: 6.6490x; 1.7058x over previous
//
#include <hip/hip_runtime.h>
#include <math.h>

#define B 2
#define CH 128
#define H 96
#define W 128
#define HP 104
#define WP 136
#define KPAD 4
#define NSHIFT 81
#define NBR 6
#define HW (H*W)         // 12288
#define HWP (HP*WP)      // 14144
#define NTILE 111        // ceil(14144/128)

typedef _Float16 h2 __attribute__((ext_vector_type(2)));
typedef _Float16 half8 __attribute__((ext_vector_type(8)));
typedef float floatx4 __attribute__((ext_vector_type(4)));

__device__ __constant__ int d_radius[NBR] = {1, 3, 5, 9, 13, 21};

__device__ __forceinline__ void async16(const _Float16* g, _Float16* l) {
    __builtin_amdgcn_global_load_lds(
        (const __attribute__((address_space(1))) unsigned int*)g,
        (__attribute__((address_space(3))) unsigned int*)l, 16, 0, 0);
}

// ---------------------------------------------------------------------------
// y[b][c][hw] (f32) -> yt16[b][hw][c] (f16) channels-last (conv GEMM input)
__global__ __launch_bounds__(256) void convert_y_kernel(const float* __restrict__ y,
                                                        _Float16* __restrict__ yt16) {
    int gid = blockIdx.x * 256 + threadIdx.x;
    if (gid >= B * HW * CH) return;
    int c = gid & 127;
    int rest = gid >> 7;
    int hw = rest % HW;
    int b = rest / HW;
    yt16[gid] = (_Float16)y[((size_t)(b * CH + c)) * HW + hw];
}

// weights[br][co][ci][tap] (f32) -> w16t[br][tap][co][ci] (f16); also zero zbuf
__global__ __launch_bounds__(256) void convert_w_kernel(const float* __restrict__ w,
                                                        _Float16* __restrict__ w16t,
                                                        _Float16* __restrict__ zbuf) {
    int gid = blockIdx.x * 256 + threadIdx.x;
    if (gid < 256) zbuf[gid] = (_Float16)0.0f;
    if (gid >= NBR * 9 * CH * CH) return;
    int ci = gid & 127;
    int co = (gid >> 7) & 127;
    int rest = gid >> 14;       // br*9 + tap
    int tap = rest % 9;
    int br = rest / 9;
    w16t[gid] = (_Float16)w[(((size_t)(br * CH + co)) * CH + ci) * 9 + tap];
}

// x[b][c][hw] f32 -> xh[b][g][pair][hw] as half2 (channels 2p, 2p+1 of group)
__global__ __launch_bounds__(256) void convert_x_kernel(const float* __restrict__ x,
                                                        h2* __restrict__ xh) {
    int gid = blockIdx.x * 256 + threadIdx.x;
    if (gid >= B * 4 * 16 * HW) return;
    int pix = gid % HW;
    int rest = gid / HW;
    int p = rest & 15;
    int bgg = rest >> 4;
    int g = bgg & 3, b = bgg >> 2;
    int c0 = g * 32 + 2 * p;
    h2 v;
    v[0] = (_Float16)x[((size_t)(b * CH + c0)) * HW + pix];
    v[1] = (_Float16)x[((size_t)(b * CH + c0 + 1)) * HW + pix];
    xh[gid] = v;
}

// ---------------------------------------------------------------------------
__global__ __launch_bounds__(256) void xn_kernel(const float* __restrict__ x,
                                                 float* __restrict__ xn) {
    int idx = blockIdx.x * 256 + threadIdx.x;
    if (idx >= B * 4 * HW) return;
    int pix = idx % HW;
    int bg  = idx / HW;
    int g = bg & 3, b = bg >> 2;
    const float* xp = x + (size_t)(b * CH + g * 32) * HW + pix;
    float s = 0.f;
    #pragma unroll
    for (int c = 0; c < 32; c++) { float v = xp[(size_t)c * HW]; s += v * v; }
    xn[idx] = sqrtf(s);
}

// yn_all[brl][b][g][pix] from f16-pair conv output ygh[brl][b][g][p][pix]
__global__ __launch_bounds__(256) void yn_kernel(const h2* __restrict__ ygh,
                                                 float* __restrict__ yn_all, int total) {
    int idx = blockIdx.x * 256 + threadIdx.x;
    if (idx >= total) return;
    int pix = idx % HWP;
    int rest = idx / HWP;        // (brl*B+b)*4+g
    const h2* yp = ygh + ((size_t)rest * 16) * HWP + pix;
    float s = 0.f;
    #pragma unroll
    for (int p = 0; p < 16; p++) {
        h2 v = yp[(size_t)p * HWP];
        float a = (float)v[0], c = (float)v[1];
        s += a * a + c * c;
    }
    yn_all[idx] = sqrtf(s);
}

// ---------------------------------------------------------------------------
// Implicit-GEMM dilated conv, f16 MFMA. 128 co x 128 pixels per block.
// Grid: (NTILE, NBR, B). Writes ygh[br][b][g][pair][pix] half2 (bias added).
__global__ __launch_bounds__(256) void conv_mfma(const _Float16* __restrict__ yt16,
                                                 const _Float16* __restrict__ w16t,
                                                 const _Float16* __restrict__ zbuf,
                                                 const float* __restrict__ biases,
                                                 h2* __restrict__ ygh) {
    const int tid = threadIdx.x;
    const int lane = tid & 63;
    const int wv = tid >> 6;
    const int tile = blockIdx.x;
    const int br = blockIdx.y;
    const int b = blockIdx.z;
    const int d = d_radius[br];
    const int px0 = tile * 128;

    __shared__ __align__(16) _Float16 Al[128 * 32];
    __shared__ __align__(16) _Float16 Bl[128 * 32];

    const int l16 = tid & 3;
    int ph[2], pw[2];
    bool pval[2];
    #pragma unroll
    for (int s = 0; s < 2; ++s) {
        int pixl = s * 64 + (tid >> 2);
        int pix = px0 + pixl;
        pval[s] = pix < HWP;
        int phh = pix / WP;
        ph[s] = phh; pw[s] = pix - phh * WP;
    }

    const _Float16* ytb = yt16 + (size_t)b * HW * CH;
    const _Float16* wbr = w16t + (size_t)br * 9 * CH * CH;

    floatx4 acc[4][4];
    #pragma unroll
    for (int i = 0; i < 4; i++)
        #pragma unroll
        for (int j = 0; j < 4; j++) {
            floatx4 z = {0.f, 0.f, 0.f, 0.f};
            acc[i][j] = z;
        }

    const int mrow = (wv & 1) * 64 + (lane & 15);
    const int ncol = (wv >> 1) * 64 + (lane & 15);
    const int kq = (lane >> 4) * 8;

    for (int tap = 0; tap < 9; ++tap) {
        const int dkh = (tap / 3 - 1) * d;
        const int dkw = (tap % 3 - 1) * d;
        const _Float16* brow[2];
        #pragma unroll
        for (int s = 0; s < 2; ++s) {
            int gr = ph[s] + dkh, gc = pw[s] + dkw;
            bool v = pval[s] && ((unsigned)gr < (unsigned)HP) && ((unsigned)gc < (unsigned)WP);
            const _Float16* p;
            if (v) {
                int yr = gr - KPAD; yr = yr < 0 ? -yr : (yr >= H ? 2 * (H - 1) - yr : yr);
                int yc = gc - KPAD; yc = yc < 0 ? -yc : (yc >= W ? 2 * (W - 1) - yc : yc);
                p = ytb + ((size_t)(yr * W + yc)) * CH + l16 * 8;
            } else {
                p = zbuf + l16 * 8;
            }
            brow[s] = p;
        }
        const _Float16* wa = wbr + tap * CH * CH + (tid >> 2) * CH + l16 * 8;

        for (int ck = 0; ck < 4; ++ck) {
            const int ci0 = ck * 32;
            async16(wa + ci0,            Al + wv * 512);
            async16(wa + 64 * CH + ci0,  Al + 2048 + wv * 512);
            async16(brow[0] + ci0,       Bl + wv * 512);
            async16(brow[1] + ci0,       Bl + 2048 + wv * 512);
            __syncthreads();

            half8 af[4], bf[4];
            #pragma unroll
            for (int i = 0; i < 4; i++) af[i] = *(const half8*)&Al[(mrow + i * 16) * 32 + kq];
            #pragma unroll
            for (int j = 0; j < 4; j++) bf[j] = *(const half8*)&Bl[(ncol + j * 16) * 32 + kq];
            #pragma unroll
            for (int i = 0; i < 4; i++)
                #pragma unroll
                for (int j = 0; j < 4; j++)
                    acc[i][j] = __builtin_amdgcn_mfma_f32_16x16x32_f16(af[i], bf[j], acc[i][j], 0, 0, 0);
            __syncthreads();
        }
    }

    // epilogue: bias + pack to half2 pairs. C layout: n=lane&15, m=(lane>>4)*4+reg
    #pragma unroll
    for (int i = 0; i < 4; i++) {
        int m0 = (wv & 1) * 64 + i * 16 + (lane >> 4) * 4;   // multiple of 4
        int g0 = (m0 >> 5);
        int pp = (m0 & 31) >> 1;
        float b0 = biases[br * CH + m0];
        float b1 = biases[br * CH + m0 + 1];
        float b2 = biases[br * CH + m0 + 2];
        float b3 = biases[br * CH + m0 + 3];
        h2* outp = ygh + (((size_t)(br * B + b) * 4 + g0) * 16 + pp) * HWP;
        #pragma unroll
        for (int j = 0; j < 4; j++) {
            int pix = px0 + (wv >> 1) * 64 + j * 16 + (lane & 15);
            if (pix < HWP) {
                h2 v0, v1;
                v0[0] = (_Float16)(acc[i][j][0] + b0);
                v0[1] = (_Float16)(acc[i][j][1] + b1);
                v1[0] = (_Float16)(acc[i][j][2] + b2);
                v1[1] = (_Float16)(acc[i][j][3] + b3);
                outp[pix] = v0;
                outp[(size_t)HWP + pix] = v1;
            }
        }
    }
}

// ---------------------------------------------------------------------------
// Correlation v2: tile 8 rows x 128 cols per block, thread = 4 cols.
// sx chunked 3x3 (acc[108]); channel pairs staged CPAIR at a time; fdot2.
// Grid: (12, 8, NBR)
#define CPAIR 4
__global__ __launch_bounds__(256) void corr2_kernel(const h2* __restrict__ xh,
                                                    const h2* __restrict__ ygh,
                                                    const float* __restrict__ xn,
                                                    const float* __restrict__ yn_all,
                                                    float* __restrict__ out) {
    const int tid = threadIdx.x;
    const int row = tid >> 5;          // 0..7
    const int col4 = (tid & 31) * 4;   // 0..124
    const int H0 = blockIdx.x * 8;
    const int bg = blockIdx.y;
    const int g = bg & 3, b = bg >> 2;
    const int brl = blockIdx.z;
    const int hh = H0 + row;

    __shared__ __align__(16) _Float16 yt[CPAIR * 340 * 8];   // CPAIR * 5440 B

    const h2* ygb = ygh + ((size_t)((brl * B + b) * 4 + g) * 16) * HWP;
    const h2* xb  = xh  + ((size_t)(b * 4 + g) * 16) * HW;
    const float* ynb = yn_all + (size_t)((brl * B + b) * 4 + g) * HWP;

    float xnv[4];
    *(floatx4*)xnv = *(const floatx4*)(xn + (size_t)(b * 4 + g) * HW + hh * W + col4);

    for (int chunk = 0; chunk < 3; ++chunk) {
        const int row0 = H0 + chunk * 3;
        float acc[108];
        #pragma unroll
        for (int s = 0; s < 108; ++s) acc[s] = 0.f;

        for (int p0 = 0; p0 < 16; p0 += CPAIR) {
            __syncthreads();
            for (int i = tid; i < CPAIR * 340; i += 256) {
                int pr = i / 340, off = i - pr * 340;
                const _Float16* src =
                    (const _Float16*)(ygb + (size_t)(p0 + pr) * HWP + row0 * WP) + off * 8;
                async16(src, yt + i * 8);
            }
            __syncthreads();
            #pragma unroll
            for (int cp = 0; cp < CPAIR; ++cp) {
                h2 x2[4];
                *(half8*)x2 = *(const half8*)(xb + (size_t)(p0 + cp) * HW + hh * W + col4);
                #pragma unroll
                for (int sx = 0; sx < 3; ++sx) {
                    h2 yv[12];
                    const _Float16* yr = yt + (cp * 1360 + (row + sx) * 136 + col4) * 2;
                    ((half8*)yv)[0] = *(const half8*)(yr);
                    ((half8*)yv)[1] = *(const half8*)(yr + 8);
                    ((half8*)yv)[2] = *(const half8*)(yr + 16);
                    #pragma unroll
                    for (int sy = 0; sy < 9; ++sy)
                        #pragma unroll
                        for (int j = 0; j < 4; ++j)
                            acc[(sx * 9 + sy) * 4 + j] = __builtin_amdgcn_fdot2(
                                x2[j], yv[sy + j], acc[(sx * 9 + sy) * 4 + j], false);
                }
            }
        }

        // epilogue for this chunk's 27 shift planes
        #pragma unroll
        for (int sxl = 0; sxl < 3; ++sxl) {
            int sx = chunk * 3 + sxl;
            float ynv[12];
            const float* yp = ynb + (size_t)(hh + sx) * WP + col4;
            *(floatx4*)&ynv[0] = *(const floatx4*)(yp);
            *(floatx4*)&ynv[4] = *(const floatx4*)(yp + 4);
            *(floatx4*)&ynv[8] = *(const floatx4*)(yp + 8);
            float* ob = out + ((size_t)(b * 24 + brl * 4 + g) * NSHIFT + sx * 9) * HW
                        + hh * W + col4;
            #pragma unroll
            for (int sy = 0; sy < 9; ++sy) {
                float o[4];
                #pragma unroll
                for (int j = 0; j < 4; ++j) {
                    float den = xnv[j] * ynv[j + sy];
                    den = den > 1e-8f ? den : 1e-8f;
                    o[j] = acc[(sxl * 9 + sy) * 4 + j] / den;
                }
                *(floatx4*)(ob + (size_t)sy * HW) = *(floatx4*)o;
            }
        }
    }
}

// ---------------------------------------------------------------------------
extern "C" void kernel_launch(void* const* d_in, const int* in_sizes, int n_in,
                              void* d_out, int out_size, void* d_ws, size_t ws_size,
                              hipStream_t stream) {
    const float* x       = (const float*)d_in[0];
    const float* y       = (const float*)d_in[1];
    const float* weights = (const float*)d_in[2];
    const float* biases  = (const float*)d_in[3];
    float* out = (float*)d_out;

    const size_t ygh_b = (size_t)NBR * B * 4 * 16 * HWP * 4;  // 43,450,368
    const size_t yn_b  = (size_t)NBR * B * 4 * HWP * 4;       //  2,715,648
    const size_t xn_b  = (size_t)B * 4 * HW * 4;              //    393,216
    const size_t yt_b  = (size_t)B * HW * CH * 2;             //  6,291,456
    const size_t wt_b  = (size_t)NBR * 9 * CH * CH * 2;       //  1,769,472
    const size_t xh_b  = (size_t)B * 4 * 16 * HW * 4;         //  6,291,456

    char* p = (char*)d_ws;
    h2* ygh       = (h2*)p;       p += ygh_b;
    float* yn_all = (float*)p;    p += yn_b;
    float* xn     = (float*)p;    p += xn_b;
    _Float16* yt16 = (_Float16*)p; p += yt_b;
    _Float16* w16t = (_Float16*)p; p += wt_b;
    h2* xh        = (h2*)p;       p += xh_b;
    _Float16* zbuf = (_Float16*)p;

    convert_y_kernel<<<(B * HW * CH + 255) / 256, 256, 0, stream>>>(y, yt16);
    convert_w_kernel<<<(NBR * 9 * CH * CH + 255) / 256, 256, 0, stream>>>(weights, w16t, zbuf);
    convert_x_kernel<<<(B * 4 * 16 * HW + 255) / 256, 256, 0, stream>>>(x, xh);
    xn_kernel<<<(B * 4 * HW + 255) / 256, 256, 0, stream>>>(x, xn);

    conv_mfma<<<dim3(NTILE, NBR, B), 256, 0, stream>>>(yt16, w16t, zbuf, biases, ygh);

    int tot = NBR * B * 4 * HWP;
    yn_kernel<<<(tot + 255) / 256, 256, 0, stream>>>(ygh, yn_all, tot);

    corr2_kernel<<<dim3(12, 8, NBR), 256, 0, stream>>>(xh, ygh, xn, yn_all, out);
}